// Round 1
// baseline (15949.068 us; speedup 1.0000x reference)
//
#include <hip/hip_runtime.h>
#include <math.h>

#define NEG_SLOPE 0.2f
#define BN_EPS 1e-5f

// ---------------------------------------------------------------------------
// float atomic max via CAS
// ---------------------------------------------------------------------------
__device__ inline void atomicMaxF(float* addr, float val) {
    unsigned int* ai = (unsigned int*)addr;
    unsigned int old = *ai;
    while (__uint_as_float(old) < val) {
        unsigned int assumed = old;
        old = atomicCAS(ai, assumed, __float_as_uint(val));
        if (old == assumed) break;
    }
}

// ---------------------------------------------------------------------------
// Simple LDS-tiled fp32 GEMM: C[M,Nc] = A[M,K] @ W[K,Nc]
// block (16,16); grid (ceil(Nc/16), ceil(M/16))
// ---------------------------------------------------------------------------
__global__ __launch_bounds__(256) void gemm16(const float* __restrict__ A,
                                              const float* __restrict__ W,
                                              float* __restrict__ C,
                                              int M, int K, int Nc) {
    __shared__ float As[16][16];
    __shared__ float Ws[16][17];
    int tx = threadIdx.x, ty = threadIdx.y;
    int row = blockIdx.y * 16 + ty;
    int col = blockIdx.x * 16 + tx;
    float acc = 0.f;
    for (int k0 = 0; k0 < K; k0 += 16) {
        As[ty][tx] = (row < M && (k0 + tx) < K) ? A[(size_t)row * K + k0 + tx] : 0.f;
        Ws[ty][tx] = ((k0 + ty) < K && col < Nc) ? W[(size_t)(k0 + ty) * Nc + col] : 0.f;
        __syncthreads();
#pragma unroll
        for (int kk = 0; kk < 16; kk++) acc += As[ty][kk] * Ws[kk][tx];
        __syncthreads();
    }
    if (row < M && col < Nc) C[(size_t)row * Nc + col] = acc;
}

// ---------------------------------------------------------------------------
// init: nmax = -inf, den = 0, agg = 0
// ---------------------------------------------------------------------------
__global__ __launch_bounds__(256) void init_k(float* nmax, float* den, float* agg,
                                              int nH, int nA) {
    int i = blockIdx.x * blockDim.x + threadIdx.x;
    if (i < nH) { nmax[i] = -INFINITY; den[i] = 0.f; }
    if (i < nA) { agg[i] = 0.f; }
}

// ---------------------------------------------------------------------------
// per-(edge,head) attention logit + segment max.
// Self-loops are virtual: edge e >= E has src=dst=e-E.
// ---------------------------------------------------------------------------
template <int H, int C>
__global__ __launch_bounds__(256) void edge_logits(const int* __restrict__ src,
                                                   const int* __restrict__ dst,
                                                   int E, int Etot,
                                                   const float* __restrict__ xl,
                                                   const float* __restrict__ xr,
                                                   const float* __restrict__ att,
                                                   float* __restrict__ ebuf,
                                                   float* __restrict__ nmax) {
    int idx = blockIdx.x * blockDim.x + threadIdx.x;
    if (idx >= Etot * H) return;
    int e = idx / H, h = idx - e * H;
    int s = (e < E) ? src[e] : (e - E);
    int d = (e < E) ? dst[e] : (e - E);
    const float* xlp = xl + (size_t)s * (H * C) + h * C;
    const float* xrp = xr + (size_t)d * (H * C) + h * C;
    const float* ap = att + h * C;
    float acc = 0.f;
#pragma unroll 4
    for (int c = 0; c < C; c++) {
        float v = xlp[c] + xrp[c];
        v = v > 0.f ? v : NEG_SLOPE * v;
        acc += v * ap[c];
    }
    ebuf[idx] = acc;
    atomicMaxF(&nmax[d * H + h], acc);
}

// ---------------------------------------------------------------------------
// ex = exp(e - max); denom += ex; agg[dst] += ex * xl[src]
// ---------------------------------------------------------------------------
template <int H, int C>
__global__ __launch_bounds__(256) void edge_agg(const int* __restrict__ src,
                                                const int* __restrict__ dst,
                                                int E, int Etot,
                                                const float* __restrict__ xl,
                                                const float* __restrict__ ebuf,
                                                const float* __restrict__ nmax,
                                                float* __restrict__ den,
                                                float* __restrict__ agg) {
    int idx = blockIdx.x * blockDim.x + threadIdx.x;
    if (idx >= Etot * H) return;
    int e = idx / H, h = idx - e * H;
    int s = (e < E) ? src[e] : (e - E);
    int d = (e < E) ? dst[e] : (e - E);
    float ex = expf(ebuf[idx] - nmax[d * H + h]);
    atomicAdd(&den[d * H + h], ex);
    const float* xlp = xl + (size_t)s * (H * C) + h * C;
    float* ag = agg + (size_t)d * (H * C) + h * C;
#pragma unroll 4
    for (int c = 0; c < C; c++) atomicAdd(&ag[c], ex * xlp[c]);
}

// ---------------------------------------------------------------------------
// epilogue with linear residual: out = BN(agg/den + bias + resA@resW + resB)
// optionally ReLU. Hd = Nc / C heads for denom indexing.
// ---------------------------------------------------------------------------
__global__ __launch_bounds__(256) void epilogue_res(const float* __restrict__ agg,
                                                    const float* __restrict__ den,
                                                    const float* __restrict__ bias,
                                                    const float* __restrict__ resA,
                                                    const float* __restrict__ resW,
                                                    const float* __restrict__ resB,
                                                    const float* __restrict__ g,
                                                    const float* __restrict__ bb,
                                                    const float* __restrict__ mm,
                                                    const float* __restrict__ vv,
                                                    float* __restrict__ out,
                                                    int N, int K, int Nc, int C,
                                                    int relu) {
    int idx = blockIdx.x * blockDim.x + threadIdx.x;
    if (idx >= N * Nc) return;
    int n = idx / Nc, j = idx - n * Nc;
    int Hd = Nc / C;
    float a = agg[idx] / den[n * Hd + j / C] + bias[j];
    float r = resB[j];
    const float* ar = resA + (size_t)n * K;
#pragma unroll 4
    for (int k = 0; k < K; k++) r += ar[k] * resW[(size_t)k * Nc + j];
    float x = a + r;
    x = (x - mm[j]) * rsqrtf(vv[j] + BN_EPS) * g[j] + bb[j];
    if (relu) x = fmaxf(x, 0.f);
    out[idx] = x;
}

// ---------------------------------------------------------------------------
// epilogue with identity residual (in-place on h)
// ---------------------------------------------------------------------------
__global__ __launch_bounds__(256) void epilogue_id(const float* __restrict__ agg,
                                                   const float* __restrict__ den,
                                                   const float* __restrict__ bias,
                                                   const float* __restrict__ g,
                                                   const float* __restrict__ bb,
                                                   const float* __restrict__ mm,
                                                   const float* __restrict__ vv,
                                                   float* __restrict__ h,
                                                   int N, int Nc, int C) {
    int idx = blockIdx.x * blockDim.x + threadIdx.x;
    if (idx >= N * Nc) return;
    int n = idx / Nc, j = idx - n * Nc;
    int Hd = Nc / C;
    float x = agg[idx] / den[n * Hd + j / C] + bias[j] + h[idx];
    x = (x - mm[j]) * rsqrtf(vv[j] + BN_EPS) * g[j] + bb[j];
    h[idx] = fmaxf(x, 0.f);
}

// ---------------------------------------------------------------------------
extern "C" void kernel_launch(void* const* d_in, const int* in_sizes, int n_in,
                              void* d_out, int out_size, void* d_ws, size_t ws_size,
                              hipStream_t stream) {
    const float* x      = (const float*)d_in[0];
    const int*   ei     = (const int*)d_in[1];
    const float* w1_src = (const float*)d_in[2];
    const float* w1_dst = (const float*)d_in[3];
    const float* att1   = (const float*)d_in[4];
    const float* b1     = (const float*)d_in[5];
    const float* bn1_g  = (const float*)d_in[6];
    const float* bn1_b  = (const float*)d_in[7];
    const float* bn1_m  = (const float*)d_in[8];
    const float* bn1_v  = (const float*)d_in[9];
    const float* res0_w = (const float*)d_in[10];
    const float* res0_b = (const float*)d_in[11];
    const float* w2_src = (const float*)d_in[12];
    const float* w2_dst = (const float*)d_in[13];
    const float* att2   = (const float*)d_in[14];
    const float* b2     = (const float*)d_in[15];
    const float* bn2_g  = (const float*)d_in[16];
    const float* bn2_b  = (const float*)d_in[17];
    const float* bn2_m  = (const float*)d_in[18];
    const float* bn2_v  = (const float*)d_in[19];
    const float* w3_src = (const float*)d_in[20];
    const float* w3_dst = (const float*)d_in[21];
    const float* att3   = (const float*)d_in[22];
    const float* b3     = (const float*)d_in[23];
    const float* bn3_g  = (const float*)d_in[24];
    const float* bn3_b  = (const float*)d_in[25];
    const float* bn3_m  = (const float*)d_in[26];
    const float* bn3_v  = (const float*)d_in[27];
    const float* res2_w = (const float*)d_in[28];
    const float* res2_b = (const float*)d_in[29];

    const int F_IN = 100, W1 = 128, OUT = 47;
    int N = in_sizes[0] / F_IN;
    int E = in_sizes[1] / 2;
    int Etot = E + N;
    const int* src = ei;
    const int* dst = ei + E;

    // workspace layout (floats); total ~118 MB
    float* ws = (float*)d_ws;
    size_t o = 0;
    float* B_xl  = ws + o; o += (size_t)N * W1;
    float* B_xr  = ws + o; o += (size_t)N * W1;
    float* B_agg = ws + o; o += (size_t)N * W1;
    float* B_h   = ws + o; o += (size_t)N * W1;
    float* B_e   = ws + o; o += (size_t)Etot * 4;
    float* B_max = ws + o; o += (size_t)N * 4;
    float* B_den = ws + o; o += (size_t)N * 4;
    (void)ws_size; (void)n_in; (void)out_size;

    dim3 gb(16, 16);
    int gM = (N + 15) / 16;

    // ---------------- layer 1: 100 -> 4x32 ----------------
    gemm16<<<dim3(W1 / 16, gM), gb, 0, stream>>>(x, w1_src, B_xl, N, F_IN, W1);
    gemm16<<<dim3(W1 / 16, gM), gb, 0, stream>>>(x, w1_dst, B_xr, N, F_IN, W1);
    {
        int nH = N * 4, nA = N * W1;
        init_k<<<(nA + 255) / 256, 256, 0, stream>>>(B_max, B_den, B_agg, nH, nA);
        int tot = Etot * 4;
        edge_logits<4, 32><<<(tot + 255) / 256, 256, 0, stream>>>(
            src, dst, E, Etot, B_xl, B_xr, att1, B_e, B_max);
        edge_agg<4, 32><<<(tot + 255) / 256, 256, 0, stream>>>(
            src, dst, E, Etot, B_xl, B_e, B_max, B_den, B_agg);
        int tn = N * W1;
        epilogue_res<<<(tn + 255) / 256, 256, 0, stream>>>(
            B_agg, B_den, b1, x, res0_w, res0_b, bn1_g, bn1_b, bn1_m, bn1_v,
            B_h, N, F_IN, W1, 32, 1);
    }

    // ---------------- layer 2: 128 -> 4x32, identity residual ----------------
    gemm16<<<dim3(W1 / 16, gM), gb, 0, stream>>>(B_h, w2_src, B_xl, N, W1, W1);
    gemm16<<<dim3(W1 / 16, gM), gb, 0, stream>>>(B_h, w2_dst, B_xr, N, W1, W1);
    {
        int nH = N * 4, nA = N * W1;
        init_k<<<(nA + 255) / 256, 256, 0, stream>>>(B_max, B_den, B_agg, nH, nA);
        int tot = Etot * 4;
        edge_logits<4, 32><<<(tot + 255) / 256, 256, 0, stream>>>(
            src, dst, E, Etot, B_xl, B_xr, att2, B_e, B_max);
        edge_agg<4, 32><<<(tot + 255) / 256, 256, 0, stream>>>(
            src, dst, E, Etot, B_xl, B_e, B_max, B_den, B_agg);
        int tn = N * W1;
        epilogue_id<<<(tn + 255) / 256, 256, 0, stream>>>(
            B_agg, B_den, b2, bn2_g, bn2_b, bn2_m, bn2_v, B_h, N, W1, 32);
    }

    // ---------------- layer 3: 128 -> 47, heads=1, linear residual ----------------
    gemm16<<<dim3((OUT + 15) / 16, gM), gb, 0, stream>>>(B_h, w3_src, B_xl, N, W1, OUT);
    gemm16<<<dim3((OUT + 15) / 16, gM), gb, 0, stream>>>(B_h, w3_dst, B_xr, N, W1, OUT);
    {
        int nH = N, nA = N * OUT;
        init_k<<<(nA + 255) / 256, 256, 0, stream>>>(B_max, B_den, B_agg, nH, nA);
        int tot = Etot;
        edge_logits<1, 47><<<(tot + 255) / 256, 256, 0, stream>>>(
            src, dst, E, Etot, B_xl, B_xr, att3, B_e, B_max);
        edge_agg<1, 47><<<(tot + 255) / 256, 256, 0, stream>>>(
            src, dst, E, Etot, B_xl, B_e, B_max, B_den, B_agg);
        int tn = N * OUT;
        epilogue_res<<<(tn + 255) / 256, 256, 0, stream>>>(
            B_agg, B_den, b3, B_h, res2_w, res2_b, bn3_g, bn3_b, bn3_m, bn3_v,
            (float*)d_out, N, W1, OUT, 47, 0);
    }
}

// Round 2
// 1297.704 us; speedup vs baseline: 12.2902x; 12.2902x over previous
//
#include <hip/hip_runtime.h>
#include <math.h>

#define NEG_SLOPE 0.2f
#define BN_EPS 1e-5f
#define SCAN_T 1024

// ---------------------------------------------------------------------------
// Simple LDS-tiled fp32 GEMM: C[M,Nc] = A[M,K] @ W[K,Nc]
// ---------------------------------------------------------------------------
__global__ __launch_bounds__(256) void gemm16(const float* __restrict__ A,
                                              const float* __restrict__ W,
                                              float* __restrict__ C,
                                              int M, int K, int Nc) {
    __shared__ float As[16][16];
    __shared__ float Ws[16][17];
    int tx = threadIdx.x, ty = threadIdx.y;
    int row = blockIdx.y * 16 + ty;
    int col = blockIdx.x * 16 + tx;
    float acc = 0.f;
    for (int k0 = 0; k0 < K; k0 += 16) {
        As[ty][tx] = (row < M && (k0 + tx) < K) ? A[(size_t)row * K + k0 + tx] : 0.f;
        Ws[ty][tx] = ((k0 + ty) < K && col < Nc) ? W[(size_t)(k0 + ty) * Nc + col] : 0.f;
        __syncthreads();
#pragma unroll
        for (int kk = 0; kk < 16; kk++) acc += As[ty][kk] * Ws[kk][tx];
        __syncthreads();
    }
    if (row < M && col < Nc) C[(size_t)row * Nc + col] = acc;
}

// ---------------------------------------------------------------------------
// CSR build: zero, histogram, scan, scatter
// ---------------------------------------------------------------------------
__global__ __launch_bounds__(256) void zero_k(int* __restrict__ p, int n) {
    int i = blockIdx.x * blockDim.x + threadIdx.x;
    if (i < n) p[i] = 0;
}

__global__ __launch_bounds__(256) void hist_k(const int* __restrict__ dst,
                                              int E, int Etot, int* __restrict__ deg) {
    int i = blockIdx.x * blockDim.x + threadIdx.x;
    if (i >= Etot) return;
    int d = (i < E) ? dst[i] : (i - E);
    atomicAdd(&deg[d], 1);
}

// single-block exclusive scan: rowptr[0..N], rowptr[N] = total
__global__ __launch_bounds__(SCAN_T) void scan_k(const int* __restrict__ deg,
                                                 int* __restrict__ rowptr, int N) {
    __shared__ int sums[SCAN_T];
    int t = threadIdx.x;
    int chunk = (N + SCAN_T - 1) / SCAN_T;
    int lo = t * chunk;
    int hi = lo + chunk; if (hi > N) hi = N;
    int s = 0;
    for (int i = lo; i < hi; i++) s += deg[i];
    sums[t] = s;
    __syncthreads();
    for (int off = 1; off < SCAN_T; off <<= 1) {
        int v = (t >= off) ? sums[t - off] : 0;
        __syncthreads();
        sums[t] += v;
        __syncthreads();
    }
    int base = (t > 0) ? sums[t - 1] : 0;
    for (int i = lo; i < hi; i++) { rowptr[i] = base; base += deg[i]; }
    if (t == SCAN_T - 1) rowptr[N] = sums[SCAN_T - 1];
}

__global__ __launch_bounds__(256) void scatter_k(const int* __restrict__ src,
                                                 const int* __restrict__ dst,
                                                 int E, int Etot,
                                                 const int* __restrict__ rowptr,
                                                 int* __restrict__ cnt,
                                                 int* __restrict__ esrc) {
    int i = blockIdx.x * blockDim.x + threadIdx.x;
    if (i >= Etot) return;
    int d = (i < E) ? dst[i] : (i - E);
    int s = (i < E) ? src[i] : (i - E);
    int pos = rowptr[d] + atomicAdd(&cnt[d], 1);
    esrc[pos] = s;
}

// ---------------------------------------------------------------------------
// GATv2 aggregation, H=4 C=32: one wave per destination node.
// lane = h*16+q owns channels (2q, 2q+1) of head h; channel idx = lane*2.
// Online softmax in registers; zero atomics. Writes normalized agg.
// ---------------------------------------------------------------------------
__global__ __launch_bounds__(256) void gat_agg4(const int* __restrict__ rowptr,
                                                const int* __restrict__ esrc,
                                                const float* __restrict__ xl,
                                                const float* __restrict__ xr,
                                                const float* __restrict__ att,
                                                float* __restrict__ out, int N) {
    int wave = blockIdx.x * 4 + (threadIdx.x >> 6);
    if (wave >= N) return;
    int lane = threadIdx.x & 63;
    int d = wave;
    float2 xrv = *(const float2*)(xr + (size_t)d * 128 + lane * 2);
    float2 av  = *(const float2*)(att + lane * 2);
    int beg = rowptr[d], end = rowptr[d + 1];
    float m = -INFINITY, den = 0.f, a0 = 0.f, a1 = 0.f;
    for (int j = beg; j < end; j++) {
        int s = esrc[j];
        float2 xlv = *(const float2*)(xl + (size_t)s * 128 + lane * 2);
        float v0 = xlv.x + xrv.x; v0 = v0 > 0.f ? v0 : NEG_SLOPE * v0;
        float v1 = xlv.y + xrv.y; v1 = v1 > 0.f ? v1 : NEG_SLOPE * v1;
        float t = v0 * av.x + v1 * av.y;
        t += __shfl_xor(t, 1);
        t += __shfl_xor(t, 2);
        t += __shfl_xor(t, 4);
        t += __shfl_xor(t, 8);
        float nm = fmaxf(m, t);
        float sc = __expf(m - nm);
        float p  = __expf(t - nm);
        den = den * sc + p;
        a0  = a0 * sc + p * xlv.x;
        a1  = a1 * sc + p * xlv.y;
        m = nm;
    }
    float inv = 1.f / den;
    float2 o; o.x = a0 * inv; o.y = a1 * inv;
    *(float2*)(out + (size_t)d * 128 + lane * 2) = o;
}

// ---------------------------------------------------------------------------
// GATv2 aggregation, H=1 C=47: one wave per dst; lane = channel (lanes>=47 idle)
// ---------------------------------------------------------------------------
__global__ __launch_bounds__(256) void gat_agg1(const int* __restrict__ rowptr,
                                                const int* __restrict__ esrc,
                                                const float* __restrict__ xl,
                                                const float* __restrict__ xr,
                                                const float* __restrict__ att,
                                                float* __restrict__ out, int N) {
    int wave = blockIdx.x * 4 + (threadIdx.x >> 6);
    if (wave >= N) return;
    int lane = threadIdx.x & 63;
    int d = wave;
    bool ok = lane < 47;
    float xrv = ok ? xr[(size_t)d * 47 + lane] : 0.f;
    float av  = ok ? att[lane] : 0.f;
    int beg = rowptr[d], end = rowptr[d + 1];
    float m = -INFINITY, den = 0.f, a0 = 0.f;
    for (int j = beg; j < end; j++) {
        int s = esrc[j];
        float xlv = ok ? xl[(size_t)s * 47 + lane] : 0.f;
        float v = xlv + xrv; v = v > 0.f ? v : NEG_SLOPE * v;
        float t = v * av;
        t += __shfl_xor(t, 1);
        t += __shfl_xor(t, 2);
        t += __shfl_xor(t, 4);
        t += __shfl_xor(t, 8);
        t += __shfl_xor(t, 16);
        t += __shfl_xor(t, 32);
        float nm = fmaxf(m, t);
        float sc = __expf(m - nm);
        float p  = __expf(t - nm);
        den = den * sc + p;
        a0  = a0 * sc + p * xlv;
        m = nm;
    }
    if (ok) out[(size_t)d * 47 + lane] = a0 / den;
}

// ---------------------------------------------------------------------------
// epilogue with linear residual: out = BN(agg + bias + resA@resW + resB) [relu]
// ---------------------------------------------------------------------------
__global__ __launch_bounds__(256) void epilogue_res(const float* __restrict__ agg,
                                                    const float* __restrict__ bias,
                                                    const float* __restrict__ resA,
                                                    const float* __restrict__ resW,
                                                    const float* __restrict__ resB,
                                                    const float* __restrict__ g,
                                                    const float* __restrict__ bb,
                                                    const float* __restrict__ mm,
                                                    const float* __restrict__ vv,
                                                    float* __restrict__ out,
                                                    int N, int K, int Nc, int relu) {
    int idx = blockIdx.x * blockDim.x + threadIdx.x;
    if (idx >= N * Nc) return;
    int n = idx / Nc, j = idx - n * Nc;
    float a = agg[idx] + bias[j];
    float r = resB[j];
    const float* ar = resA + (size_t)n * K;
#pragma unroll 4
    for (int k = 0; k < K; k++) r += ar[k] * resW[(size_t)k * Nc + j];
    float x = a + r;
    x = (x - mm[j]) * rsqrtf(vv[j] + BN_EPS) * g[j] + bb[j];
    if (relu) x = fmaxf(x, 0.f);
    out[idx] = x;
}

// ---------------------------------------------------------------------------
// epilogue with identity residual (in-place on h)
// ---------------------------------------------------------------------------
__global__ __launch_bounds__(256) void epilogue_id(const float* __restrict__ agg,
                                                   const float* __restrict__ bias,
                                                   const float* __restrict__ g,
                                                   const float* __restrict__ bb,
                                                   const float* __restrict__ mm,
                                                   const float* __restrict__ vv,
                                                   float* __restrict__ h,
                                                   int N, int Nc) {
    int idx = blockIdx.x * blockDim.x + threadIdx.x;
    if (idx >= N * Nc) return;
    int j = idx % Nc;
    float x = agg[idx] + bias[j] + h[idx];
    x = (x - mm[j]) * rsqrtf(vv[j] + BN_EPS) * g[j] + bb[j];
    h[idx] = fmaxf(x, 0.f);
}

// ---------------------------------------------------------------------------
extern "C" void kernel_launch(void* const* d_in, const int* in_sizes, int n_in,
                              void* d_out, int out_size, void* d_ws, size_t ws_size,
                              hipStream_t stream) {
    const float* x      = (const float*)d_in[0];
    const int*   ei     = (const int*)d_in[1];
    const float* w1_src = (const float*)d_in[2];
    const float* w1_dst = (const float*)d_in[3];
    const float* att1   = (const float*)d_in[4];
    const float* b1     = (const float*)d_in[5];
    const float* bn1_g  = (const float*)d_in[6];
    const float* bn1_b  = (const float*)d_in[7];
    const float* bn1_m  = (const float*)d_in[8];
    const float* bn1_v  = (const float*)d_in[9];
    const float* res0_w = (const float*)d_in[10];
    const float* res0_b = (const float*)d_in[11];
    const float* w2_src = (const float*)d_in[12];
    const float* w2_dst = (const float*)d_in[13];
    const float* att2   = (const float*)d_in[14];
    const float* b2     = (const float*)d_in[15];
    const float* bn2_g  = (const float*)d_in[16];
    const float* bn2_b  = (const float*)d_in[17];
    const float* bn2_m  = (const float*)d_in[18];
    const float* bn2_v  = (const float*)d_in[19];
    const float* w3_src = (const float*)d_in[20];
    const float* w3_dst = (const float*)d_in[21];
    const float* att3   = (const float*)d_in[22];
    const float* b3     = (const float*)d_in[23];
    const float* bn3_g  = (const float*)d_in[24];
    const float* bn3_b  = (const float*)d_in[25];
    const float* bn3_m  = (const float*)d_in[26];
    const float* bn3_v  = (const float*)d_in[27];
    const float* res2_w = (const float*)d_in[28];
    const float* res2_b = (const float*)d_in[29];

    const int F_IN = 100, W1 = 128, OUT = 47;
    int N = in_sizes[0] / F_IN;
    int E = in_sizes[1] / 2;
    int Etot = E + N;
    const int* src = ei;
    const int* dst = ei + E;

    // workspace layout
    float* ws = (float*)d_ws;
    size_t o = 0;
    float* B_xl  = ws + o; o += (size_t)N * W1;
    float* B_xr  = ws + o; o += (size_t)N * W1;
    float* B_agg = ws + o; o += (size_t)N * W1;
    float* B_h   = ws + o; o += (size_t)N * W1;
    int* I_deg    = (int*)(ws + o); o += N;
    int* I_cnt    = (int*)(ws + o); o += N;
    int* I_rowptr = (int*)(ws + o); o += N + 1;
    int* I_esrc   = (int*)(ws + o); o += Etot;
    (void)ws_size; (void)n_in; (void)out_size;

    // ---- build CSR (dst-sorted) once per call ----
    zero_k<<<(2 * N + 255) / 256, 256, 0, stream>>>(I_deg, N);
    zero_k<<<(N + 255) / 256, 256, 0, stream>>>(I_cnt, N);
    hist_k<<<(Etot + 255) / 256, 256, 0, stream>>>(dst, E, Etot, I_deg);
    scan_k<<<1, SCAN_T, 0, stream>>>(I_deg, I_rowptr, N);
    scatter_k<<<(Etot + 255) / 256, 256, 0, stream>>>(src, dst, E, Etot, I_rowptr,
                                                      I_cnt, I_esrc);

    dim3 gb(16, 16);
    int gM = (N + 15) / 16;
    int aggGrid = (N + 3) / 4;

    // ---------------- layer 1: 100 -> 4x32 ----------------
    gemm16<<<dim3(W1 / 16, gM), gb, 0, stream>>>(x, w1_src, B_xl, N, F_IN, W1);
    gemm16<<<dim3(W1 / 16, gM), gb, 0, stream>>>(x, w1_dst, B_xr, N, F_IN, W1);
    gat_agg4<<<aggGrid, 256, 0, stream>>>(I_rowptr, I_esrc, B_xl, B_xr, att1, B_agg, N);
    epilogue_res<<<(N * W1 + 255) / 256, 256, 0, stream>>>(
        B_agg, b1, x, res0_w, res0_b, bn1_g, bn1_b, bn1_m, bn1_v,
        B_h, N, F_IN, W1, 1);

    // ---------------- layer 2: 128 -> 4x32, identity residual ----------------
    gemm16<<<dim3(W1 / 16, gM), gb, 0, stream>>>(B_h, w2_src, B_xl, N, W1, W1);
    gemm16<<<dim3(W1 / 16, gM), gb, 0, stream>>>(B_h, w2_dst, B_xr, N, W1, W1);
    gat_agg4<<<aggGrid, 256, 0, stream>>>(I_rowptr, I_esrc, B_xl, B_xr, att2, B_agg, N);
    epilogue_id<<<(N * W1 + 255) / 256, 256, 0, stream>>>(
        B_agg, b2, bn2_g, bn2_b, bn2_m, bn2_v, B_h, N, W1);

    // ---------------- layer 3: 128 -> 47, heads=1, linear residual ----------------
    gemm16<<<dim3((OUT + 15) / 16, gM), gb, 0, stream>>>(B_h, w3_src, B_xl, N, W1, OUT);
    gemm16<<<dim3((OUT + 15) / 16, gM), gb, 0, stream>>>(B_h, w3_dst, B_xr, N, W1, OUT);
    gat_agg1<<<aggGrid, 256, 0, stream>>>(I_rowptr, I_esrc, B_xl, B_xr, att3, B_agg, N);
    epilogue_res<<<(N * OUT + 255) / 256, 256, 0, stream>>>(
        B_agg, b3, B_h, res2_w, res2_b, bn3_g, bn3_b, bn3_m, bn3_v,
        (float*)d_out, N, W1, OUT, 0);
}

// Round 3
// 724.099 us; speedup vs baseline: 22.0261x; 1.7922x over previous
//
#include <hip/hip_runtime.h>
#include <math.h>

#define NEG_SLOPE 0.2f
#define BN_EPS 1e-5f
#define SCAN_T 1024

typedef short short8 __attribute__((ext_vector_type(8)));
typedef float float4v __attribute__((ext_vector_type(4)));

// float -> bf16 bits, round-to-nearest-even
static __device__ inline unsigned short f2bf(float f) {
    unsigned u = __float_as_uint(f);
    u = u + 0x7fffu + ((u >> 16) & 1u);
    return (unsigned short)(u >> 16);
}

// ---------------------------------------------------------------------------
// CSR build: zero, histogram, scan, scatter
// ---------------------------------------------------------------------------
__global__ __launch_bounds__(256) void zero_k(int* __restrict__ p, int n) {
    int i = blockIdx.x * blockDim.x + threadIdx.x;
    if (i < n) p[i] = 0;
}

__global__ __launch_bounds__(256) void hist_k(const int* __restrict__ dst,
                                              int E, int Etot, int* __restrict__ deg) {
    int i = blockIdx.x * blockDim.x + threadIdx.x;
    if (i >= Etot) return;
    int d = (i < E) ? dst[i] : (i - E);
    atomicAdd(&deg[d], 1);
}

__global__ __launch_bounds__(SCAN_T) void scan_k(const int* __restrict__ deg,
                                                 int* __restrict__ rowptr, int N) {
    __shared__ int sums[SCAN_T];
    int t = threadIdx.x;
    int chunk = (N + SCAN_T - 1) / SCAN_T;
    int lo = t * chunk;
    int hi = lo + chunk; if (hi > N) hi = N;
    int s = 0;
    for (int i = lo; i < hi; i++) s += deg[i];
    sums[t] = s;
    __syncthreads();
    for (int off = 1; off < SCAN_T; off <<= 1) {
        int v = (t >= off) ? sums[t - off] : 0;
        __syncthreads();
        sums[t] += v;
        __syncthreads();
    }
    int base = (t > 0) ? sums[t - 1] : 0;
    for (int i = lo; i < hi; i++) { rowptr[i] = base; base += deg[i]; }
    if (t == SCAN_T - 1) rowptr[N] = sums[SCAN_T - 1];
}

__global__ __launch_bounds__(256) void scatter_k(const int* __restrict__ src,
                                                 const int* __restrict__ dst,
                                                 int E, int Etot,
                                                 const int* __restrict__ rowptr,
                                                 int* __restrict__ cnt,
                                                 int* __restrict__ esrc) {
    int i = blockIdx.x * blockDim.x + threadIdx.x;
    if (i >= Etot) return;
    int d = (i < E) ? dst[i] : (i - E);
    int s = (i < E) ? src[i] : (i - E);
    int pos = rowptr[d] + atomicAdd(&cnt[d], 1);
    esrc[pos] = s;
}

// ---------------------------------------------------------------------------
// Pack [p0|p1|p2] (each [Ksrc, wX] fp32 row-major) into MFMA B-fragment-major
// bf16: out[((kt*ntiles+nt)*64 + quad*16+nr)*8 + j] = B[kt*32+quad*8+j][nt*16+nr]
// Rows >= Ksrc and cols >= w0+w1+w2 are zero. Kpad, Ncat multiples of 32/16.
// ---------------------------------------------------------------------------
__global__ __launch_bounds__(256) void pack_w(const float* __restrict__ p0,
                                              const float* __restrict__ p1,
                                              const float* __restrict__ p2,
                                              int w0, int w1, int w2,
                                              int Ksrc, int Kpad, int Ncat,
                                              unsigned short* __restrict__ out) {
    int idx = blockIdx.x * blockDim.x + threadIdx.x;
    if (idx >= Kpad * Ncat) return;
    int k = idx / Ncat, n = idx - k * Ncat;
    float v = 0.f;
    if (k < Ksrc) {
        if (n < w0) v = p0[(size_t)k * w0 + n];
        else if (n < w0 + w1) v = p1[(size_t)k * w1 + (n - w0)];
        else if (w2 > 0 && n < w0 + w1 + w2) v = p2[(size_t)k * w2 + (n - w0 - w1)];
    }
    int kt = k >> 5, kr = k & 31;
    int quad = kr >> 3, j = kr & 7;
    int nt = n >> 4, nr = n & 15;
    int ntiles = Ncat >> 4;
    out[((size_t)(kt * ntiles + nt) * 64 + quad * 16 + nr) * 8 + j] = f2bf(v);
}

// convert fp32 [N,Ksrc] -> bf16 [N,Kpad] (zero-padded)
__global__ __launch_bounds__(256) void conv_bf(const float* __restrict__ x,
                                               unsigned short* __restrict__ out,
                                               int N, int Ksrc, int Kpad) {
    int idx = blockIdx.x * blockDim.x + threadIdx.x;
    if (idx >= N * Kpad) return;
    int n = idx / Kpad, k = idx - n * Kpad;
    out[idx] = f2bf(k < Ksrc ? x[(size_t)n * Ksrc + k] : 0.f);
}

// ---------------------------------------------------------------------------
// MFMA bf16 GEMM: C[M,Ncat] = A[M,Kpad] @ B(packed). One wave computes a
// 16 x (16*NT) tile. A frag from global (16B/lane), B frag packed-coalesced.
// M must be a multiple of 16; Kpad multiple of 32; Ncat multiple of 16*NT.
// ---------------------------------------------------------------------------
template <int NT>
__global__ __launch_bounds__(256) void mfma_gemm(const unsigned short* __restrict__ A,
                                                 const unsigned short* __restrict__ Bp,
                                                 float* __restrict__ C,
                                                 int M, int Kpad, int Ncat) {
    int wid = (blockIdx.x * blockDim.x + threadIdx.x) >> 6;
    int lane = threadIdx.x & 63;
    int ngroups = Ncat / (16 * NT);
    int mtiles = M >> 4;
    int mt = wid / ngroups;
    int ng = wid - mt * ngroups;
    if (mt >= mtiles) return;
    int quad = lane >> 4;
    int nr = lane & 15;
    int row = mt * 16 + nr;
    int ntiles = Ncat >> 4;

    float4v acc[NT];
#pragma unroll
    for (int t = 0; t < NT; t++) acc[t] = (float4v){0.f, 0.f, 0.f, 0.f};

    for (int k0 = 0; k0 < Kpad; k0 += 32) {
        short8 a = *(const short8*)(A + (size_t)row * Kpad + k0 + quad * 8);
        int kt = k0 >> 5;
        const unsigned short* bbase =
            Bp + ((size_t)(kt * ntiles + ng * NT) * 64 + lane) * 8;
#pragma unroll
        for (int t = 0; t < NT; t++) {
            short8 b = *(const short8*)(bbase + (size_t)t * 64 * 8);
            acc[t] = __builtin_amdgcn_mfma_f32_16x16x32_bf16(a, b, acc[t], 0, 0, 0);
        }
    }
#pragma unroll
    for (int t = 0; t < NT; t++) {
        int col = (ng * NT + t) * 16 + nr;
        size_t base = (size_t)(mt * 16 + quad * 4) * Ncat + col;
#pragma unroll
        for (int r = 0; r < 4; r++) C[base + (size_t)r * Ncat] = acc[t][r];
    }
}

// ---------------------------------------------------------------------------
// GATv2 aggregation, H=4 C=32: one wave per destination node; xl/xr live in
// the cat-GEMM output with row stride ld (xl at col 0, xr at col xr_off).
// ---------------------------------------------------------------------------
__global__ __launch_bounds__(256) void gat_agg4(const int* __restrict__ rowptr,
                                                const int* __restrict__ esrc,
                                                const float* __restrict__ xbase,
                                                int ld, int xr_off,
                                                const float* __restrict__ att,
                                                float* __restrict__ out, int N) {
    int wave = blockIdx.x * 4 + (threadIdx.x >> 6);
    if (wave >= N) return;
    int lane = threadIdx.x & 63;
    int d = wave;
    float2 xrv = *(const float2*)(xbase + (size_t)d * ld + xr_off + lane * 2);
    float2 av  = *(const float2*)(att + lane * 2);
    int beg = rowptr[d], end = rowptr[d + 1];
    float m = -INFINITY, den = 0.f, a0 = 0.f, a1 = 0.f;
    for (int j = beg; j < end; j++) {
        int s = esrc[j];
        float2 xlv = *(const float2*)(xbase + (size_t)s * ld + lane * 2);
        float v0 = xlv.x + xrv.x; v0 = v0 > 0.f ? v0 : NEG_SLOPE * v0;
        float v1 = xlv.y + xrv.y; v1 = v1 > 0.f ? v1 : NEG_SLOPE * v1;
        float t = v0 * av.x + v1 * av.y;
        t += __shfl_xor(t, 1);
        t += __shfl_xor(t, 2);
        t += __shfl_xor(t, 4);
        t += __shfl_xor(t, 8);
        float nm = fmaxf(m, t);
        float sc = __expf(m - nm);
        float p  = __expf(t - nm);
        den = den * sc + p;
        a0  = a0 * sc + p * xlv.x;
        a1  = a1 * sc + p * xlv.y;
        m = nm;
    }
    float inv = 1.f / den;
    float2 o; o.x = a0 * inv; o.y = a1 * inv;
    *(float2*)(out + (size_t)d * 128 + lane * 2) = o;
}

// ---------------------------------------------------------------------------
// GATv2 aggregation, H=1 C=47: one wave per dst; lane = channel
// ---------------------------------------------------------------------------
__global__ __launch_bounds__(256) void gat_agg1(const int* __restrict__ rowptr,
                                                const int* __restrict__ esrc,
                                                const float* __restrict__ xbase,
                                                int ld, int xr_off,
                                                const float* __restrict__ att,
                                                float* __restrict__ out, int N) {
    int wave = blockIdx.x * 4 + (threadIdx.x >> 6);
    if (wave >= N) return;
    int lane = threadIdx.x & 63;
    int d = wave;
    bool ok = lane < 47;
    int li = ok ? lane : 0;
    float xrv = ok ? xbase[(size_t)d * ld + xr_off + li] : 0.f;
    float av  = ok ? att[li] : 0.f;
    int beg = rowptr[d], end = rowptr[d + 1];
    float m = -INFINITY, den = 0.f, a0 = 0.f;
    for (int j = beg; j < end; j++) {
        int s = esrc[j];
        float xlv = ok ? xbase[(size_t)s * ld + li] : 0.f;
        float v = xlv + xrv; v = v > 0.f ? v : NEG_SLOPE * v;
        float t = v * av;
        t += __shfl_xor(t, 1);
        t += __shfl_xor(t, 2);
        t += __shfl_xor(t, 4);
        t += __shfl_xor(t, 8);
        t += __shfl_xor(t, 16);
        t += __shfl_xor(t, 32);
        float nm = fmaxf(m, t);
        float sc = __expf(m - nm);
        float p  = __expf(t - nm);
        den = den * sc + p;
        a0  = a0 * sc + p * xlv;
        m = nm;
    }
    if (ok) out[(size_t)d * 47 + lane] = a0 / den;
}

// ---------------------------------------------------------------------------
// Layer-1 epilogue: h = relu(BN(agg + b1 + res + res_b)); writes fp32 + bf16
// res read from cat-GEMM output C at col offset res_off, row stride ld.
// ---------------------------------------------------------------------------
__global__ __launch_bounds__(256) void epi1_k(const float* __restrict__ agg,
                                              const float* __restrict__ C,
                                              int ld, int res_off,
                                              const float* __restrict__ bias,
                                              const float* __restrict__ resB,
                                              const float* __restrict__ g,
                                              const float* __restrict__ bb,
                                              const float* __restrict__ mm,
                                              const float* __restrict__ vv,
                                              float* __restrict__ h,
                                              unsigned short* __restrict__ hbf,
                                              int N) {
    int idx = blockIdx.x * blockDim.x + threadIdx.x;
    if (idx >= N * 128) return;
    int n = idx >> 7, j = idx & 127;
    float x = agg[idx] + bias[j] + C[(size_t)n * ld + res_off + j] + resB[j];
    x = (x - mm[j]) * rsqrtf(vv[j] + BN_EPS) * g[j] + bb[j];
    x = fmaxf(x, 0.f);
    h[idx] = x;
    hbf[idx] = f2bf(x);
}

// Layer-2 epilogue: h2 = relu(BN(agg + b2 + h)); writes bf16 only
__global__ __launch_bounds__(256) void epi2_k(const float* __restrict__ agg,
                                              const float* __restrict__ h,
                                              const float* __restrict__ bias,
                                              const float* __restrict__ g,
                                              const float* __restrict__ bb,
                                              const float* __restrict__ mm,
                                              const float* __restrict__ vv,
                                              unsigned short* __restrict__ h2bf,
                                              int N) {
    int idx = blockIdx.x * blockDim.x + threadIdx.x;
    if (idx >= N * 128) return;
    int j = idx & 127;
    float x = agg[idx] + bias[j] + h[idx];
    x = (x - mm[j]) * rsqrtf(vv[j] + BN_EPS) * g[j] + bb[j];
    h2bf[idx] = f2bf(fmaxf(x, 0.f));
}

// Layer-3 epilogue: out = BN(agg + b3 + res + res_b)  (no relu)
__global__ __launch_bounds__(256) void epi3_k(const float* __restrict__ agg,
                                              const float* __restrict__ C,
                                              int ld, int res_off,
                                              const float* __restrict__ bias,
                                              const float* __restrict__ resB,
                                              const float* __restrict__ g,
                                              const float* __restrict__ bb,
                                              const float* __restrict__ mm,
                                              const float* __restrict__ vv,
                                              float* __restrict__ out,
                                              int N) {
    int idx = blockIdx.x * blockDim.x + threadIdx.x;
    if (idx >= N * 47) return;
    int n = idx / 47, j = idx - n * 47;
    float x = agg[idx] + bias[j] + C[(size_t)n * ld + res_off + j] + resB[j];
    x = (x - mm[j]) * rsqrtf(vv[j] + BN_EPS) * g[j] + bb[j];
    out[idx] = x;
}

// ---------------------------------------------------------------------------
extern "C" void kernel_launch(void* const* d_in, const int* in_sizes, int n_in,
                              void* d_out, int out_size, void* d_ws, size_t ws_size,
                              hipStream_t stream) {
    const float* x      = (const float*)d_in[0];
    const int*   ei     = (const int*)d_in[1];
    const float* w1_src = (const float*)d_in[2];
    const float* w1_dst = (const float*)d_in[3];
    const float* att1   = (const float*)d_in[4];
    const float* b1     = (const float*)d_in[5];
    const float* bn1_g  = (const float*)d_in[6];
    const float* bn1_b  = (const float*)d_in[7];
    const float* bn1_m  = (const float*)d_in[8];
    const float* bn1_v  = (const float*)d_in[9];
    const float* res0_w = (const float*)d_in[10];
    const float* res0_b = (const float*)d_in[11];
    const float* w2_src = (const float*)d_in[12];
    const float* w2_dst = (const float*)d_in[13];
    const float* att2   = (const float*)d_in[14];
    const float* b2     = (const float*)d_in[15];
    const float* bn2_g  = (const float*)d_in[16];
    const float* bn2_b  = (const float*)d_in[17];
    const float* bn2_m  = (const float*)d_in[18];
    const float* bn2_v  = (const float*)d_in[19];
    const float* w3_src = (const float*)d_in[20];
    const float* w3_dst = (const float*)d_in[21];
    const float* att3   = (const float*)d_in[22];
    const float* b3     = (const float*)d_in[23];
    const float* bn3_g  = (const float*)d_in[24];
    const float* bn3_b  = (const float*)d_in[25];
    const float* bn3_m  = (const float*)d_in[26];
    const float* bn3_v  = (const float*)d_in[27];
    const float* res2_w = (const float*)d_in[28];
    const float* res2_b = (const float*)d_in[29];

    const int F_IN = 100, W1 = 128, OUT = 47;
    const int KP = 128;                 // padded K for all layers
    const int NC1 = 384, NC2 = 256, NC3 = 144;  // cat widths (NC3: 47*3=141 -> 144)
    int N = in_sizes[0] / F_IN;
    int E = in_sizes[1] / 2;
    int Etot = E + N;
    const int* src = ei;
    const int* dst = ei + E;

    // ---- workspace layout (float units; all offsets multiples of 4 floats) ----
    float* ws = (float*)d_ws;
    size_t o = 0;
    float* B_C    = ws + o; o += (size_t)N * NC1;          // cat-GEMM out (max width)
    float* B_agg  = ws + o; o += (size_t)N * W1;           // agg output
    float* B_h    = ws + o; o += (size_t)N * W1;           // layer-1 h (fp32)
    unsigned short* A_bf = (unsigned short*)(ws + o); o += (size_t)N * KP / 2;  // act bf16
    unsigned short* Wb1  = (unsigned short*)(ws + o); o += (size_t)KP * NC1 / 2;
    unsigned short* Wb2  = (unsigned short*)(ws + o); o += (size_t)KP * NC2 / 2;
    unsigned short* Wb3  = (unsigned short*)(ws + o); o += (size_t)KP * NC3 / 2;
    int* I_deg    = (int*)(ws + o); o += N;
    int* I_cnt    = (int*)(ws + o); o += N;
    int* I_rowptr = (int*)(ws + o); o += N + 4;
    int* I_esrc   = (int*)(ws + o); o += Etot;
    (void)ws_size; (void)n_in; (void)out_size;

    // ---- CSR build ----
    zero_k<<<(N + 255) / 256, 256, 0, stream>>>(I_deg, N);
    zero_k<<<(N + 255) / 256, 256, 0, stream>>>(I_cnt, N);
    hist_k<<<(Etot + 255) / 256, 256, 0, stream>>>(dst, E, Etot, I_deg);
    scan_k<<<1, SCAN_T, 0, stream>>>(I_deg, I_rowptr, N);
    scatter_k<<<(Etot + 255) / 256, 256, 0, stream>>>(src, dst, E, Etot, I_rowptr,
                                                      I_cnt, I_esrc);

    // ---- weight packing (bf16, fragment-major) ----
    pack_w<<<(KP * NC1 + 255) / 256, 256, 0, stream>>>(
        w1_src, w1_dst, res0_w, W1, W1, W1, F_IN, KP, NC1, Wb1);
    pack_w<<<(KP * NC2 + 255) / 256, 256, 0, stream>>>(
        w2_src, w2_dst, nullptr, W1, W1, 0, W1, KP, NC2, Wb2);
    pack_w<<<(KP * NC3 + 255) / 256, 256, 0, stream>>>(
        w3_src, w3_dst, res2_w, OUT, OUT, OUT, W1, KP, NC3, Wb3);

    int aggGrid = (N + 3) / 4;
    int mtiles = (N + 15) / 16;

    // ---------------- layer 1 ----------------
    conv_bf<<<(N * KP + 255) / 256, 256, 0, stream>>>(x, A_bf, N, F_IN, KP);
    {
        int waves = mtiles * (NC1 / 64);
        mfma_gemm<4><<<(waves * 64 + 255) / 256, 256, 0, stream>>>(
            A_bf, Wb1, B_C, N, KP, NC1);
    }
    gat_agg4<<<aggGrid, 256, 0, stream>>>(I_rowptr, I_esrc, B_C, NC1, 128, att1,
                                          B_agg, N);
    epi1_k<<<(N * W1 + 255) / 256, 256, 0, stream>>>(
        B_agg, B_C, NC1, 256, b1, res0_b, bn1_g, bn1_b, bn1_m, bn1_v,
        B_h, A_bf, N);

    // ---------------- layer 2 ----------------
    {
        int waves = mtiles * (NC2 / 64);
        mfma_gemm<4><<<(waves * 64 + 255) / 256, 256, 0, stream>>>(
            A_bf, Wb2, B_C, N, KP, NC2);
    }
    gat_agg4<<<aggGrid, 256, 0, stream>>>(I_rowptr, I_esrc, B_C, NC2, 128, att2,
                                          B_agg, N);
    epi2_k<<<(N * W1 + 255) / 256, 256, 0, stream>>>(
        B_agg, B_h, b2, bn2_g, bn2_b, bn2_m, bn2_v, A_bf, N);

    // ---------------- layer 3 ----------------
    {
        int waves = mtiles * (NC3 / 48);
        mfma_gemm<3><<<(waves * 64 + 255) / 256, 256, 0, stream>>>(
            A_bf, Wb3, B_C, N, KP, NC3);
    }
    gat_agg1<<<aggGrid, 256, 0, stream>>>(I_rowptr, I_esrc, B_C, NC3, 47, att3,
                                          B_agg, N);
    epi3_k<<<(N * OUT + 255) / 256, 256, 0, stream>>>(
        B_agg, B_C, NC3, 94, b3, res2_b, bn3_g, bn3_b, bn3_m, bn3_v,
        (float*)d_out, N);
}

// Round 4
// 586.329 us; speedup vs baseline: 27.2015x; 1.2350x over previous
//
#include <hip/hip_runtime.h>
#include <math.h>

#define NEG_SLOPE 0.2f
#define BN_EPS 1e-5f
#define SCAN_T 1024

typedef short short8 __attribute__((ext_vector_type(8)));
typedef float float4v __attribute__((ext_vector_type(4)));

// float -> bf16 bits, round-to-nearest-even
static __device__ inline unsigned short f2bf(float f) {
    unsigned u = __float_as_uint(f);
    u = u + 0x7fffu + ((u >> 16) & 1u);
    return (unsigned short)(u >> 16);
}
static __device__ inline float bf2f(unsigned short u) {
    return __uint_as_float((unsigned)u << 16);
}

// ---------------------------------------------------------------------------
// CSR build: zero, histogram, scan, scatter
// ---------------------------------------------------------------------------
__global__ __launch_bounds__(256) void zero_k(int* __restrict__ p, int n) {
    int i = blockIdx.x * blockDim.x + threadIdx.x;
    if (i < n) p[i] = 0;
}

__global__ __launch_bounds__(256) void hist_k(const int* __restrict__ dst,
                                              int E, int Etot, int* __restrict__ deg) {
    int i = blockIdx.x * blockDim.x + threadIdx.x;
    if (i >= Etot) return;
    int d = (i < E) ? dst[i] : (i - E);
    atomicAdd(&deg[d], 1);
}

__global__ __launch_bounds__(SCAN_T) void scan_k(const int* __restrict__ deg,
                                                 int* __restrict__ rowptr, int N) {
    __shared__ int sums[SCAN_T];
    int t = threadIdx.x;
    int chunk = (N + SCAN_T - 1) / SCAN_T;
    int lo = t * chunk;
    int hi = lo + chunk; if (hi > N) hi = N;
    int s = 0;
    for (int i = lo; i < hi; i++) s += deg[i];
    sums[t] = s;
    __syncthreads();
    for (int off = 1; off < SCAN_T; off <<= 1) {
        int v = (t >= off) ? sums[t - off] : 0;
        __syncthreads();
        sums[t] += v;
        __syncthreads();
    }
    int base = (t > 0) ? sums[t - 1] : 0;
    for (int i = lo; i < hi; i++) { rowptr[i] = base; base += deg[i]; }
    if (t == SCAN_T - 1) rowptr[N] = sums[SCAN_T - 1];
}

__global__ __launch_bounds__(256) void scatter_k(const int* __restrict__ src,
                                                 const int* __restrict__ dst,
                                                 int E, int Etot,
                                                 const int* __restrict__ rowptr,
                                                 int* __restrict__ cnt,
                                                 int* __restrict__ esrc) {
    int i = blockIdx.x * blockDim.x + threadIdx.x;
    if (i >= Etot) return;
    int d = (i < E) ? dst[i] : (i - E);
    int s = (i < E) ? src[i] : (i - E);
    int pos = rowptr[d] + atomicAdd(&cnt[d], 1);
    esrc[pos] = s;
}

// ---------------------------------------------------------------------------
// Pack [p0|p1|p2] (each [Ksrc, wX] fp32 row-major) into MFMA B-fragment-major
// bf16: out[((kt*ntiles+nt)*64 + quad*16+nr)*8 + j] = B[kt*32+quad*8+j][nt*16+nr]
// ---------------------------------------------------------------------------
__global__ __launch_bounds__(256) void pack_w(const float* __restrict__ p0,
                                              const float* __restrict__ p1,
                                              const float* __restrict__ p2,
                                              int w0, int w1, int w2,
                                              int Ksrc, int Kpad, int Ncat,
                                              unsigned short* __restrict__ out) {
    int idx = blockIdx.x * blockDim.x + threadIdx.x;
    if (idx >= Kpad * Ncat) return;
    int k = idx / Ncat, n = idx - k * Ncat;
    float v = 0.f;
    if (k < Ksrc) {
        if (n < w0) v = p0[(size_t)k * w0 + n];
        else if (n < w0 + w1) v = p1[(size_t)k * w1 + (n - w0)];
        else if (w2 > 0 && n < w0 + w1 + w2) v = p2[(size_t)k * w2 + (n - w0 - w1)];
    }
    int kt = k >> 5, kr = k & 31;
    int quad = kr >> 3, j = kr & 7;
    int nt = n >> 4, nr = n & 15;
    int ntiles = Ncat >> 4;
    out[((size_t)(kt * ntiles + nt) * 64 + quad * 16 + nr) * 8 + j] = f2bf(v);
}

// convert fp32 [N,Ksrc] -> bf16 [N,Kpad] (zero-padded)
__global__ __launch_bounds__(256) void conv_bf(const float* __restrict__ x,
                                               unsigned short* __restrict__ out,
                                               int N, int Ksrc, int Kpad) {
    int idx = blockIdx.x * blockDim.x + threadIdx.x;
    if (idx >= N * Kpad) return;
    int n = idx / Kpad, k = idx - n * Kpad;
    out[idx] = f2bf(k < Ksrc ? x[(size_t)n * Ksrc + k] : 0.f);
}

// ---------------------------------------------------------------------------
// MFMA bf16 GEMM: one wave = 16 x (16*NT) tile.
// Cols < res_off -> bf16 into XLR (with optional +1 col shift at >= bf_remap);
// cols in [res_off, ncat_valid) -> fp32 into RES. Cols >= ncat_valid dropped.
// ---------------------------------------------------------------------------
template <int NT>
__global__ __launch_bounds__(256) void mfma_gemm(const unsigned short* __restrict__ A,
                                                 const unsigned short* __restrict__ Bp,
                                                 unsigned short* __restrict__ XLR,
                                                 float* __restrict__ RES,
                                                 int M, int Kpad, int Ncat,
                                                 int ncat_valid, int res_off,
                                                 int bf_remap, int bf_stride,
                                                 int res_stride) {
    int wid = (blockIdx.x * blockDim.x + threadIdx.x) >> 6;
    int lane = threadIdx.x & 63;
    int ngroups = Ncat / (16 * NT);
    int mtiles = M >> 4;
    int mt = wid / ngroups;
    int ng = wid - mt * ngroups;
    if (mt >= mtiles) return;
    int quad = lane >> 4;
    int nr = lane & 15;
    int row = mt * 16 + nr;
    int ntiles = Ncat >> 4;

    float4v acc[NT];
#pragma unroll
    for (int t = 0; t < NT; t++) acc[t] = (float4v){0.f, 0.f, 0.f, 0.f};

    for (int k0 = 0; k0 < Kpad; k0 += 32) {
        short8 a = *(const short8*)(A + (size_t)row * Kpad + k0 + quad * 8);
        int kt = k0 >> 5;
        const unsigned short* bbase =
            Bp + ((size_t)(kt * ntiles + ng * NT) * 64 + lane) * 8;
#pragma unroll
        for (int t = 0; t < NT; t++) {
            short8 b = *(const short8*)(bbase + (size_t)t * 64 * 8);
            acc[t] = __builtin_amdgcn_mfma_f32_16x16x32_bf16(a, b, acc[t], 0, 0, 0);
        }
    }
    int rowb = mt * 16 + quad * 4;
#pragma unroll
    for (int t = 0; t < NT; t++) {
        int col = (ng * NT + t) * 16 + nr;
        if (col >= ncat_valid) continue;
        if (col < res_off) {
            int bc = (bf_remap != 0 && col >= bf_remap) ? col + 1 : col;
#pragma unroll
            for (int r = 0; r < 4; r++)
                XLR[(size_t)(rowb + r) * bf_stride + bc] = f2bf(acc[t][r]);
        } else {
            int rc = col - res_off;
#pragma unroll
            for (int r = 0; r < 4; r++)
                RES[(size_t)(rowb + r) * res_stride + rc] = acc[t][r];
        }
    }
}

// ---------------------------------------------------------------------------
// GATv2 aggregation, H=4 C=32: one wave per dst node; xl|xr bf16 rows of 256
// (xl cols 0..127, xr cols 128..255). No running max (logits bounded),
// 4x-unrolled edge loop for gather/shfl ILP. Zero atomics.
// ---------------------------------------------------------------------------
__global__ __launch_bounds__(256) void gat_agg4(const int* __restrict__ rowptr,
                                                const int* __restrict__ esrc,
                                                const unsigned short* __restrict__ xlr,
                                                const float* __restrict__ att,
                                                float* __restrict__ out, int N) {
    int wave = blockIdx.x * 4 + (threadIdx.x >> 6);
    if (wave >= N) return;
    int lane = threadIdx.x & 63;
    int d = wave;
    unsigned xr2 = *(const unsigned*)(xlr + (size_t)d * 256 + 128 + lane * 2);
    float xr0 = bf2f((unsigned short)(xr2 & 0xffff));
    float xr1 = bf2f((unsigned short)(xr2 >> 16));
    float2 av = *(const float2*)(att + lane * 2);
    int beg = rowptr[d], end = rowptr[d + 1];
    float den = 0.f, a0 = 0.f, a1 = 0.f;
    int j = beg;
    for (; j + 4 <= end; j += 4) {
        unsigned xv[4];
#pragma unroll
        for (int u = 0; u < 4; u++) {
            int s = esrc[j + u];
            xv[u] = *(const unsigned*)(xlr + (size_t)s * 256 + lane * 2);
        }
#pragma unroll
        for (int u = 0; u < 4; u++) {
            float x0 = bf2f((unsigned short)(xv[u] & 0xffff));
            float x1 = bf2f((unsigned short)(xv[u] >> 16));
            float v0 = x0 + xr0; v0 = v0 > 0.f ? v0 : NEG_SLOPE * v0;
            float v1 = x1 + xr1; v1 = v1 > 0.f ? v1 : NEG_SLOPE * v1;
            float t = v0 * av.x + v1 * av.y;
            t += __shfl_xor(t, 1);
            t += __shfl_xor(t, 2);
            t += __shfl_xor(t, 4);
            t += __shfl_xor(t, 8);
            float p = __expf(t);
            den += p;
            a0 = fmaf(p, x0, a0);
            a1 = fmaf(p, x1, a1);
        }
    }
    for (; j < end; j++) {
        int s = esrc[j];
        unsigned xv = *(const unsigned*)(xlr + (size_t)s * 256 + lane * 2);
        float x0 = bf2f((unsigned short)(xv & 0xffff));
        float x1 = bf2f((unsigned short)(xv >> 16));
        float v0 = x0 + xr0; v0 = v0 > 0.f ? v0 : NEG_SLOPE * v0;
        float v1 = x1 + xr1; v1 = v1 > 0.f ? v1 : NEG_SLOPE * v1;
        float t = v0 * av.x + v1 * av.y;
        t += __shfl_xor(t, 1);
        t += __shfl_xor(t, 2);
        t += __shfl_xor(t, 4);
        t += __shfl_xor(t, 8);
        float p = __expf(t);
        den += p;
        a0 = fmaf(p, x0, a0);
        a1 = fmaf(p, x1, a1);
    }
    float inv = 1.f / den;
    float2 o; o.x = a0 * inv; o.y = a1 * inv;
    *(float2*)(out + (size_t)d * 128 + lane * 2) = o;
}

// ---------------------------------------------------------------------------
// GATv2 aggregation, H=1 C=47: bf16 rows of 96 (xl 0..46, xr 48..94)
// ---------------------------------------------------------------------------
__global__ __launch_bounds__(256) void gat_agg1(const int* __restrict__ rowptr,
                                                const int* __restrict__ esrc,
                                                const unsigned short* __restrict__ xlr,
                                                const float* __restrict__ att,
                                                float* __restrict__ out, int N) {
    int wave = blockIdx.x * 4 + (threadIdx.x >> 6);
    if (wave >= N) return;
    int lane = threadIdx.x & 63;
    int d = wave;
    bool ok = lane < 47;
    int li = ok ? lane : 0;
    float xrv = ok ? bf2f(xlr[(size_t)d * 96 + 48 + li]) : 0.f;
    float av  = ok ? att[li] : 0.f;
    int beg = rowptr[d], end = rowptr[d + 1];
    float den = 0.f, a0 = 0.f;
    int j = beg;
    for (; j + 4 <= end; j += 4) {
        float xv[4];
#pragma unroll
        for (int u = 0; u < 4; u++) {
            int s = esrc[j + u];
            xv[u] = ok ? bf2f(xlr[(size_t)s * 96 + li]) : 0.f;
        }
#pragma unroll
        for (int u = 0; u < 4; u++) {
            float v = xv[u] + xrv; v = v > 0.f ? v : NEG_SLOPE * v;
            float t = v * av;
            t += __shfl_xor(t, 1);
            t += __shfl_xor(t, 2);
            t += __shfl_xor(t, 4);
            t += __shfl_xor(t, 8);
            t += __shfl_xor(t, 16);
            t += __shfl_xor(t, 32);
            float p = __expf(t);
            den += p;
            a0 = fmaf(p, xv[u], a0);
        }
    }
    for (; j < end; j++) {
        int s = esrc[j];
        float xv = ok ? bf2f(xlr[(size_t)s * 96 + li]) : 0.f;
        float v = xv + xrv; v = v > 0.f ? v : NEG_SLOPE * v;
        float t = v * av;
        t += __shfl_xor(t, 1);
        t += __shfl_xor(t, 2);
        t += __shfl_xor(t, 4);
        t += __shfl_xor(t, 8);
        t += __shfl_xor(t, 16);
        t += __shfl_xor(t, 32);
        float p = __expf(t);
        den += p;
        a0 = fmaf(p, xv, a0);
    }
    if (ok) out[(size_t)d * 47 + lane] = a0 / den;
}

// ---------------------------------------------------------------------------
// Layer-1 epilogue: h = relu(BN(agg + b1 + res + res_b)); writes fp32 + bf16
// ---------------------------------------------------------------------------
__global__ __launch_bounds__(256) void epi1_k(const float* __restrict__ agg,
                                              const float* __restrict__ RES,
                                              const float* __restrict__ bias,
                                              const float* __restrict__ resB,
                                              const float* __restrict__ g,
                                              const float* __restrict__ bb,
                                              const float* __restrict__ mm,
                                              const float* __restrict__ vv,
                                              float* __restrict__ h,
                                              unsigned short* __restrict__ hbf,
                                              int N) {
    int idx = blockIdx.x * blockDim.x + threadIdx.x;
    if (idx >= N * 128) return;
    int j = idx & 127;
    float x = agg[idx] + bias[j] + RES[idx] + resB[j];
    x = (x - mm[j]) * rsqrtf(vv[j] + BN_EPS) * g[j] + bb[j];
    x = fmaxf(x, 0.f);
    h[idx] = x;
    hbf[idx] = f2bf(x);
}

// Layer-2 epilogue: h2 = relu(BN(agg + b2 + h)); writes bf16 only
__global__ __launch_bounds__(256) void epi2_k(const float* __restrict__ agg,
                                              const float* __restrict__ h,
                                              const float* __restrict__ bias,
                                              const float* __restrict__ g,
                                              const float* __restrict__ bb,
                                              const float* __restrict__ mm,
                                              const float* __restrict__ vv,
                                              unsigned short* __restrict__ h2bf,
                                              int N) {
    int idx = blockIdx.x * blockDim.x + threadIdx.x;
    if (idx >= N * 128) return;
    int j = idx & 127;
    float x = agg[idx] + bias[j] + h[idx];
    x = (x - mm[j]) * rsqrtf(vv[j] + BN_EPS) * g[j] + bb[j];
    h2bf[idx] = f2bf(fmaxf(x, 0.f));
}

// Layer-3 epilogue: out = BN(agg + b3 + res + res_b)  (no relu)
__global__ __launch_bounds__(256) void epi3_k(const float* __restrict__ agg,
                                              const float* __restrict__ RES,
                                              const float* __restrict__ bias,
                                              const float* __restrict__ resB,
                                              const float* __restrict__ g,
                                              const float* __restrict__ bb,
                                              const float* __restrict__ mm,
                                              const float* __restrict__ vv,
                                              float* __restrict__ out,
                                              int N) {
    int idx = blockIdx.x * blockDim.x + threadIdx.x;
    if (idx >= N * 47) return;
    int n = idx / 47, j = idx - n * 47;
    float x = agg[idx] + bias[j] + RES[(size_t)n * 48 + j] + resB[j];
    x = (x - mm[j]) * rsqrtf(vv[j] + BN_EPS) * g[j] + bb[j];
    out[idx] = x;
}

// ---------------------------------------------------------------------------
extern "C" void kernel_launch(void* const* d_in, const int* in_sizes, int n_in,
                              void* d_out, int out_size, void* d_ws, size_t ws_size,
                              hipStream_t stream) {
    const float* x      = (const float*)d_in[0];
    const int*   ei     = (const int*)d_in[1];
    const float* w1_src = (const float*)d_in[2];
    const float* w1_dst = (const float*)d_in[3];
    const float* att1   = (const float*)d_in[4];
    const float* b1     = (const float*)d_in[5];
    const float* bn1_g  = (const float*)d_in[6];
    const float* bn1_b  = (const float*)d_in[7];
    const float* bn1_m  = (const float*)d_in[8];
    const float* bn1_v  = (const float*)d_in[9];
    const float* res0_w = (const float*)d_in[10];
    const float* res0_b = (const float*)d_in[11];
    const float* w2_src = (const float*)d_in[12];
    const float* w2_dst = (const float*)d_in[13];
    const float* att2   = (const float*)d_in[14];
    const float* b2     = (const float*)d_in[15];
    const float* bn2_g  = (const float*)d_in[16];
    const float* bn2_b  = (const float*)d_in[17];
    const float* bn2_m  = (const float*)d_in[18];
    const float* bn2_v  = (const float*)d_in[19];
    const float* w3_src = (const float*)d_in[20];
    const float* w3_dst = (const float*)d_in[21];
    const float* att3   = (const float*)d_in[22];
    const float* b3     = (const float*)d_in[23];
    const float* bn3_g  = (const float*)d_in[24];
    const float* bn3_b  = (const float*)d_in[25];
    const float* bn3_m  = (const float*)d_in[26];
    const float* bn3_v  = (const float*)d_in[27];
    const float* res2_w = (const float*)d_in[28];
    const float* res2_b = (const float*)d_in[29];

    const int F_IN = 100, W1 = 128, OUT = 47;
    const int KP = 128;
    const int NC1 = 384, NC2 = 256, NC3 = 144;
    int N = in_sizes[0] / F_IN;
    int E = in_sizes[1] / 2;
    int Etot = E + N;
    const int* src = ei;
    const int* dst = ei + E;

    // ---- workspace layout (float units) ----
    float* ws = (float*)d_ws;
    size_t o = 0;
    unsigned short* XLR = (unsigned short*)(ws + o); o += (size_t)N * 128;  // [N,256] bf16
    float* B_res = ws + o; o += (size_t)N * 128;   // residual cols fp32
    float* B_agg = ws + o; o += (size_t)N * 128;
    float* B_h   = ws + o; o += (size_t)N * 128;
    unsigned short* A_bf = (unsigned short*)(ws + o); o += (size_t)N * 64;  // [N,128] bf16
    unsigned short* Wb1  = (unsigned short*)(ws + o); o += (size_t)KP * NC1 / 2;
    unsigned short* Wb2  = (unsigned short*)(ws + o); o += (size_t)KP * NC2 / 2;
    unsigned short* Wb3  = (unsigned short*)(ws + o); o += (size_t)KP * NC3 / 2;
    int* I_deg    = (int*)(ws + o); o += N;
    int* I_cnt    = (int*)(ws + o); o += N;   // contiguous with I_deg: zeroed together
    int* I_rowptr = (int*)(ws + o); o += N + 4;
    int* I_esrc   = (int*)(ws + o); o += Etot;
    (void)ws_size; (void)n_in; (void)out_size;

    // ---- CSR build ----
    zero_k<<<(2 * N + 255) / 256, 256, 0, stream>>>(I_deg, 2 * N);
    hist_k<<<(Etot + 255) / 256, 256, 0, stream>>>(dst, E, Etot, I_deg);
    scan_k<<<1, SCAN_T, 0, stream>>>(I_deg, I_rowptr, N);
    scatter_k<<<(Etot + 255) / 256, 256, 0, stream>>>(src, dst, E, Etot, I_rowptr,
                                                      I_cnt, I_esrc);

    // ---- weight packing (bf16, fragment-major) ----
    pack_w<<<(KP * NC1 + 255) / 256, 256, 0, stream>>>(
        w1_src, w1_dst, res0_w, W1, W1, W1, F_IN, KP, NC1, Wb1);
    pack_w<<<(KP * NC2 + 255) / 256, 256, 0, stream>>>(
        w2_src, w2_dst, nullptr, W1, W1, 0, W1, KP, NC2, Wb2);
    pack_w<<<(KP * NC3 + 255) / 256, 256, 0, stream>>>(
        w3_src, w3_dst, res2_w, OUT, OUT, OUT, W1, KP, NC3, Wb3);

    int aggGrid = (N + 3) / 4;
    int mtiles = (N + 15) / 16;

    // ---------------- layer 1 ----------------
    conv_bf<<<(N * KP + 255) / 256, 256, 0, stream>>>(x, A_bf, N, F_IN, KP);
    {
        int waves = mtiles * (NC1 / 64);
        mfma_gemm<4><<<(waves * 64 + 255) / 256, 256, 0, stream>>>(
            A_bf, Wb1, XLR, B_res, N, KP, NC1, 384, 256, 0, 256, 128);
    }
    gat_agg4<<<aggGrid, 256, 0, stream>>>(I_rowptr, I_esrc, XLR, att1, B_agg, N);
    epi1_k<<<(N * W1 + 255) / 256, 256, 0, stream>>>(
        B_agg, B_res, b1, res0_b, bn1_g, bn1_b, bn1_m, bn1_v, B_h, A_bf, N);

    // ---------------- layer 2 ----------------
    {
        int waves = mtiles * (NC2 / 64);
        mfma_gemm<4><<<(waves * 64 + 255) / 256, 256, 0, stream>>>(
            A_bf, Wb2, XLR, B_res, N, KP, NC2, 256, 256, 0, 256, 128);
    }
    gat_agg4<<<aggGrid, 256, 0, stream>>>(I_rowptr, I_esrc, XLR, att2, B_agg, N);
    epi2_k<<<(N * W1 + 255) / 256, 256, 0, stream>>>(
        B_agg, B_h, b2, bn2_g, bn2_b, bn2_m, bn2_v, A_bf, N);

    // ---------------- layer 3 ----------------
    {
        int waves = mtiles * (NC3 / 48);
        mfma_gemm<3><<<(waves * 64 + 255) / 256, 256, 0, stream>>>(
            A_bf, Wb3, XLR, B_res, N, KP, NC3, 141, 94, 47, 96, 48);
    }
    gat_agg1<<<aggGrid, 256, 0, stream>>>(I_rowptr, I_esrc, XLR, att3, B_agg, N);
    epi3_k<<<(N * OUT + 255) / 256, 256, 0, stream>>>(
        B_agg, B_res, b3, res2_b, bn3_g, bn3_b, bn3_m, bn3_v, (float*)d_out, N);
}